// Round 7
// baseline (2594.932 us; speedup 1.0000x reference)
//
#include <hip/hip_runtime.h>
#include <hip/hip_bf16.h>
#include <stddef.h>

// Problem constants
constexpr int E_ = 8;
constexpr int C_ = 1024;
constexpr int M_ = 2048;
constexpr int H_ = 8192;
constexpr int O_ = 2048;

typedef __bf16 bf16;
typedef __bf16 bf16x4 __attribute__((ext_vector_type(4)));
typedef __bf16 bf16x8 __attribute__((ext_vector_type(8)));
typedef float  f32x4  __attribute__((ext_vector_type(4)));

#define GLOAD16(src, dst)                                                        \
    __builtin_amdgcn_global_load_lds(                                            \
        (const __attribute__((address_space(1))) void*)(src),                    \
        (__attribute__((address_space(3))) void*)(dst), 16, 0, 0)

#define BARRIER()  __builtin_amdgcn_s_barrier()
#define LGKM0()    do { asm volatile("s_waitcnt lgkmcnt(0)" ::: "memory");       \
                        __builtin_amdgcn_sched_barrier(0); } while (0)
#define VMCNT(n)   asm volatile("s_waitcnt vmcnt(" #n ")" ::: "memory")

// ---------------------------------------------------------------------------
// fp32 -> bf16 convert (grid-stride, 64B-read/32B-write per lane per iter)
// ---------------------------------------------------------------------------
__global__ __launch_bounds__(256)
void cvt_f32_bf16(const float* __restrict__ in, bf16* __restrict__ out, size_t n)
{
    size_t i = ((size_t)blockIdx.x * blockDim.x + threadIdx.x) * 16;
    const size_t stride = (size_t)gridDim.x * blockDim.x * 16;
    for (; i < n; i += stride) {
        f32x4 v0 = *(const f32x4*)(in + i);
        f32x4 v1 = *(const f32x4*)(in + i + 4);
        f32x4 v2 = *(const f32x4*)(in + i + 8);
        f32x4 v3 = *(const f32x4*)(in + i + 12);
        bf16x8 o0, o1;
#pragma unroll
        for (int j = 0; j < 4; ++j) {
            o0[j] = (bf16)v0[j]; o0[j + 4] = (bf16)v1[j];
            o1[j] = (bf16)v2[j]; o1[j + 4] = (bf16)v3[j];
        }
        *(bf16x8*)(out + i)     = o0;
        *(bf16x8*)(out + i + 8) = o1;
    }
}

// ---------------------------------------------------------------------------
// Transpose+convert: W2 [E, H, O] fp32 -> W2t [gridDim.z, O, H] bf16
// ---------------------------------------------------------------------------
__global__ __launch_bounds__(256)
void transpose_w2(const float* __restrict__ W2, bf16* __restrict__ W2t, int e0)
{
    const int e  = e0 + blockIdx.z;
    const int oo = blockIdx.x;  // O/64
    const int ho = blockIdx.y;  // H/64
    const int tid = threadIdx.x;

    __shared__ bf16 t[64][72];  // 144B rows: 16B-aligned bf16x8 reads

    const float* src = W2 + (size_t)e * H_ * O_ + (size_t)(ho * 64) * O_ + oo * 64;
#pragma unroll
    for (int p = 0; p < 4; ++p) {
        const int h  = p * 16 + (tid >> 4);
        const int o4 = (tid & 15) * 4;
        f32x4 v = *(const f32x4*)(src + (size_t)h * O_ + o4);
#pragma unroll
        for (int q = 0; q < 4; ++q) t[o4 + q][h] = (bf16)v[q];
    }
    __syncthreads();

    bf16* dst = W2t + (size_t)blockIdx.z * O_ * H_ + (size_t)(oo * 64) * H_ + ho * 64;
#pragma unroll
    for (int p2 = 0; p2 < 2; ++p2) {
        const int o  = p2 * 32 + (tid >> 3);
        const int h8 = (tid & 7) * 8;
        bf16x8 v = *(const bf16x8*)(&t[o][h8]);
        *(bf16x8*)(dst + (size_t)o * H_ + h8) = v;
    }
}

// ---------------------------------------------------------------------------
// 256x256-tile 8-phase GEMM, BK=64, 128 KiB LDS, 1 block/CU (r3-proven).
// Used for gemm2 (K=8192).
// ---------------------------------------------------------------------------
template<int KDIM, bool RELU_BF16>
__global__ __launch_bounds__(512, 2)
void gemm256(const bf16* __restrict__ A, const bf16* __restrict__ B,
             const float* __restrict__ bias, void* __restrict__ OutP,
             int nBM, int nBN)
{
    extern __shared__ char smem[];                  // 131072 B
    constexpr int K2  = KDIM * 2;
    constexpr int NIT = KDIM / 128;

    const int tid  = threadIdx.x;
    const int lane = tid & 63;
    const int wid  = tid >> 6;
    const int wr = wid >> 2, wc = wid & 3;
    const int fr = lane & 15, fq = lane >> 4;

    const int nwg = gridDim.x;
    const int cpx = nwg >> 3;
    const int b0  = blockIdx.x;
    const int wg  = (b0 & 7) * cpx + (b0 >> 3);
    const int per_e = nBM * nBN;
    const int e  = wg / per_e;
    const int rr = wg - e * per_e;
    const int bn = rr / nBM;
    const int bm = rr - bn * nBM;
    const int MROWS = nBM * 256;
    const int NROWS = nBN * 256;

    const char* Apan = (const char*)(A + (size_t)e * MROWS * KDIM + (size_t)bm * 256 * KDIM);
    const char* Bpan = (const char*)(B + (size_t)e * NROWS * KDIM + (size_t)bn * 256 * KDIM);

    const int r0  = tid >> 3;
    const int wsw = ((tid & 7) << 4) ^ ((r0 & 7) << 4);

    auto stageA = [&](int gk, int comp) {
        char* lds = smem + (gk & 1) * 65536 + comp * 16384 + tid * 16;
        const char* src = Apan + (size_t)((comp << 7) + r0) * K2 + (size_t)gk * 128 + wsw;
        GLOAD16(src, lds);
        GLOAD16(src + (size_t)64 * K2, lds + 8192);
    };
    auto stageB = [&](int gk, int comp2) {
        char* lds = smem + (gk & 1) * 65536 + 32768 + comp2 * 16384 + tid * 16;
        const char* src = Bpan + (size_t)((comp2 << 7) + r0) * K2 + (size_t)gk * 128 + wsw;
        GLOAD16(src, lds);
        GLOAD16(src + (size_t)64 * K2, lds + 8192);
    };

    const int frq = fr & 7;
    const int cA0 = ((fq    ) ^ frq) << 4;
    const int cA1 = ((4 | fq) ^ frq) << 4;
    const int aoff = wr * 16384 + fr * 128;
    const int boff = 32768 + (wc >> 1) * 16384 + (wc & 1) * 8192 + fr * 128;

    bf16x8 av[4][2];
    bf16x8 bv[4][2];
    f32x4 acc[8][4];
#pragma unroll
    for (int m = 0; m < 8; ++m)
#pragma unroll
        for (int n = 0; n < 4; ++n) acc[m][n] = (f32x4){0.f, 0.f, 0.f, 0.f};

    auto loadA = [&](const char* base, int mh) {
#pragma unroll
        for (int mm = 0; mm < 4; ++mm) {
            const char* p = base + aoff + (mh * 4 + mm) * 2048;
            av[mm][0] = *(const bf16x8*)(p + cA0);
            av[mm][1] = *(const bf16x8*)(p + cA1);
        }
    };
    auto loadB = [&](const char* base, int nh) {
#pragma unroll
        for (int nn = 0; nn < 2; ++nn) {
            const char* p = base + boff + (nh * 2 + nn) * 2048;
            bv[nh * 2 + nn][0] = *(const bf16x8*)(p + cA0);
            bv[nh * 2 + nn][1] = *(const bf16x8*)(p + cA1);
        }
    };
    auto mmaq = [&](int mh, int nh) {
        __builtin_amdgcn_s_setprio(1);
#pragma unroll
        for (int mm = 0; mm < 4; ++mm)
#pragma unroll
            for (int nn = 0; nn < 2; ++nn) {
                const int m = mh * 4 + mm, n = nh * 2 + nn;
                acc[m][n] = __builtin_amdgcn_mfma_f32_16x16x32_bf16(av[mm][0], bv[n][0], acc[m][n], 0, 0, 0);
                acc[m][n] = __builtin_amdgcn_mfma_f32_16x16x32_bf16(av[mm][1], bv[n][1], acc[m][n], 0, 0, 0);
            }
        __builtin_amdgcn_s_setprio(0);
    };

    stageB(0, 0); stageB(0, 1); stageA(0, 0); stageA(0, 1);
    stageB(1, 0); stageB(1, 1);
    VMCNT(4);
    BARRIER();

    for (int t = 0; t < NIT; ++t) {
        const bool nl = (t + 1 < NIT);
        const char* d0b = smem;
        const char* d1b = smem + 65536;
        const int ga = 2 * t + 1;
        const int gb = 2 * t + 2;
        const int gc = 2 * t + 3;

        loadB(d0b, 0); loadA(d0b, 0);       // ph0
        stageA(ga, 0);
        BARRIER(); LGKM0();
        mmaq(0, 0);
        BARRIER();

        loadB(d0b, 1);                      // ph1
        stageA(ga, 1);
        BARRIER(); LGKM0();
        mmaq(0, 1);
        BARRIER();

        loadA(d0b, 1);                      // ph2
        if (nl) stageB(gb, 0);
        BARRIER(); LGKM0();
        mmaq(1, 1);
        BARRIER();

        if (nl) stageB(gb, 1);              // ph3
        BARRIER(); LGKM0();
        mmaq(1, 0);
        if (nl) { VMCNT(4); } else { VMCNT(0); }
        BARRIER();

        loadB(d1b, 0); loadA(d1b, 0);       // ph4
        if (nl) stageA(gb, 0);
        BARRIER(); LGKM0();
        mmaq(0, 0);
        BARRIER();

        loadB(d1b, 1);                      // ph5
        if (nl) stageA(gb, 1);
        BARRIER(); LGKM0();
        mmaq(0, 1);
        BARRIER();

        loadA(d1b, 1);                      // ph6
        if (nl) stageB(gc, 0);
        BARRIER(); LGKM0();
        mmaq(1, 1);
        BARRIER();

        if (nl) stageB(gc, 1);              // ph7
        BARRIER(); LGKM0();
        mmaq(1, 0);
        if (nl) {
            VMCNT(4);
            BARRIER();
        }
    }

    const int gr0 = bm * 256 + wr * 128;
    const int gc0 = bn * 256 + wc * 64;
    if constexpr (RELU_BF16) {
        bf16* Out = (bf16*)OutP;
#pragma unroll
        for (int n = 0; n < 4; ++n) {
            const int col = gc0 + n * 16 + fr;
            const float bb = bias[(size_t)e * NROWS + col];
#pragma unroll
            for (int m = 0; m < 8; ++m)
#pragma unroll
                for (int j = 0; j < 4; ++j) {
                    float v = acc[m][n][j] + bb;
                    v = v > 0.f ? v : 0.f;
                    const int row = gr0 + m * 16 + fq * 4 + j;
                    Out[((size_t)e * MROWS + row) * NROWS + col] = (bf16)v;
                }
        }
    } else {
        float* Out = (float*)OutP;
#pragma unroll
        for (int n = 0; n < 4; ++n) {
            const int col = gc0 + n * 16 + fr;
            const float bb = bias[(size_t)e * NROWS + col];
#pragma unroll
            for (int m = 0; m < 8; ++m)
#pragma unroll
                for (int j = 0; j < 4; ++j) {
                    const int row = gr0 + m * 16 + fq * 4 + j;
                    Out[((size_t)e * MROWS + row) * NROWS + col] = acc[m][n][j] + bb;
                }
        }
    }
}

// ---------------------------------------------------------------------------
// 256x256-tile GEMM, BK=32, 64 KiB LDS -> 2 blocks/CU (16 waves): cross-block
// overlap hides barrier/vmcnt/prologue stalls. Used for gemm1 (K=2048).
// LDS: buf g&1 (32 KiB): A@0 (16 KiB = 256 rows x 64B), B@16K.
// Swizzle: 16B chunk c of 64B row r stored at c^(r&3) (bijective per 1 KiB
// block -> conflict-free ds_read_b128); applied on pre-swizzled gload source
// and on the fragment-read address.
// Per K-tile g (3 barrier-phases):
//  ph0: ds_read B0(2)+A0(4) | stageA(g+1) -> bar,lgkm0 -> 8 MFMA -> bar
//  ph1: ds_read B1(2)                     -> bar,lgkm0 -> 8 MFMA -> bar
//  ph2: ds_read A1(4) | stageB(g+2)       -> bar,lgkm0 -> 16 MFMA
//       -> VMCNT(2 if B(g+2) staged else 0) -> bar
// Hazards: A(g+1) write (ph0) is >=2 barriers after region's last read
// ((g-1).ph2, LGKM0-drained); B(g+2) write (ph2) >=1 barrier after B(g)'s
// last read (ph1). End-of-tile VMCNT retires exactly through tile g+1's
// operands (only B(g+2) remains in flight). Prologue stages tiles 0,1.
// ---------------------------------------------------------------------------
template<int KDIM, bool RELU_BF16>
__global__ __launch_bounds__(512, 4)
void gemm256_bk32(const bf16* __restrict__ A, const bf16* __restrict__ B,
                  const float* __restrict__ bias, void* __restrict__ OutP,
                  int nBM, int nBN)
{
    extern __shared__ char smem[];                  // 65536 B
    constexpr int K2 = KDIM * 2;
    constexpr int NT = KDIM / 32;                   // K-tiles

    const int tid  = threadIdx.x;
    const int lane = tid & 63;
    const int wid  = tid >> 6;
    const int wr = wid >> 2, wc = wid & 3;
    const int fr = lane & 15, fq = lane >> 4;

    const int nwg = gridDim.x;
    const int cpx = nwg >> 3;
    const int b0  = blockIdx.x;
    const int wg  = (b0 & 7) * cpx + (b0 >> 3);
    const int per_e = nBM * nBN;
    const int e  = wg / per_e;
    const int rr = wg - e * per_e;
    const int bn = rr / nBM;
    const int bm = rr - bn * nBM;      // bm fastest: B-panel sharers same XCD
    const int MROWS = nBM * 256;
    const int NROWS = nBN * 256;

    const char* Apan = (const char*)(A + (size_t)e * MROWS * KDIM + (size_t)bm * 256 * KDIM);
    const char* Bpan = (const char*)(B + (size_t)e * NROWS * KDIM + (size_t)bn * 256 * KDIM);

    // staging: 16 KiB/region, 512 thr x 16B x 2 gloads; rows r0, r0+128
    const int r0  = tid >> 2;                       // 0..127
    const int wsw = (((tid & 3) ^ (r0 & 3)) << 4);

    auto stageA = [&](int gk) {
        char* lds = smem + (gk & 1) * 32768 + tid * 16;
        const char* src = Apan + (size_t)r0 * K2 + (size_t)gk * 64 + wsw;
        GLOAD16(src, lds);
        GLOAD16(src + (size_t)128 * K2, lds + 8192);
    };
    auto stageB = [&](int gk) {
        char* lds = smem + (gk & 1) * 32768 + 16384 + tid * 16;
        const char* src = Bpan + (size_t)r0 * K2 + (size_t)gk * 64 + wsw;
        GLOAD16(src, lds);
        GLOAD16(src + (size_t)128 * K2, lds + 8192);
    };

    // fragment reads: row stride 64B = 4 chunks; chunk fq stored at fq^(r&3)
    const int cA   = ((fq ^ (fr & 3)) << 4);
    const int aoff = wr * 8192 + fr * 64;           // A: wave row-half + frag row
    const int boff = 16384 + wc * 4096 + fr * 64;   // B: wave col-quarter

    bf16x8 av[4];
    bf16x8 bv[4];
    f32x4 acc[8][4];
#pragma unroll
    for (int m = 0; m < 8; ++m)
#pragma unroll
        for (int n = 0; n < 4; ++n) acc[m][n] = (f32x4){0.f, 0.f, 0.f, 0.f};

    auto loadA = [&](const char* base, int mh) {
#pragma unroll
        for (int mm = 0; mm < 4; ++mm)
            av[mm] = *(const bf16x8*)(base + aoff + (mh * 4 + mm) * 1024 + cA);
    };
    auto loadB = [&](const char* base, int nh) {
#pragma unroll
        for (int nn = 0; nn < 2; ++nn)
            bv[nh * 2 + nn] = *(const bf16x8*)(base + boff + (nh * 2 + nn) * 1024 + cA);
    };
    auto mmaq8 = [&](int mh, int nh) {
        __builtin_amdgcn_s_setprio(1);
#pragma unroll
        for (int mm = 0; mm < 4; ++mm)
#pragma unroll
            for (int nn = 0; nn < 2; ++nn)
                acc[mh * 4 + mm][nh * 2 + nn] = __builtin_amdgcn_mfma_f32_16x16x32_bf16(
                    av[mm], bv[nh * 2 + nn], acc[mh * 4 + mm][nh * 2 + nn], 0, 0, 0);
        __builtin_amdgcn_s_setprio(0);
    };

    // prologue: tiles 0 and 1 fully staged (8 loads); retire tile 0
    stageA(0); stageB(0); stageA(1); stageB(1);
    VMCNT(4);
    BARRIER();

    for (int g = 0; g < NT; ++g) {
        const char* base = smem + (g & 1) * 32768;
        const bool sA = (g >= 1) && (g + 1 < NT);   // tile0's A(1) came from prologue
        const bool sB = (g + 2 < NT);

        loadB(base, 0); loadA(base, 0);             // ph0
        if (sA) stageA(g + 1);
        BARRIER(); LGKM0();
        mmaq8(0, 0);
        BARRIER();

        loadB(base, 1);                             // ph1
        BARRIER(); LGKM0();
        mmaq8(0, 1);
        BARRIER();

        loadA(base, 1);                             // ph2
        if (sB) stageB(g + 2);
        BARRIER(); LGKM0();
        mmaq8(1, 1);
        mmaq8(1, 0);
        if (g + 1 < NT) {
            if (sB) { VMCNT(2); } else { VMCNT(0); }
            BARRIER();
        }
    }

    const int gr0 = bm * 256 + wr * 128;
    const int gc0 = bn * 256 + wc * 64;
    if constexpr (RELU_BF16) {
        bf16* Out = (bf16*)OutP;
#pragma unroll
        for (int n = 0; n < 4; ++n) {
            const int col = gc0 + n * 16 + fr;
            const float bb = bias[(size_t)e * NROWS + col];
#pragma unroll
            for (int m = 0; m < 8; ++m)
#pragma unroll
                for (int j = 0; j < 4; ++j) {
                    float v = acc[m][n][j] + bb;
                    v = v > 0.f ? v : 0.f;
                    const int row = gr0 + m * 16 + fq * 4 + j;
                    Out[((size_t)e * MROWS + row) * NROWS + col] = (bf16)v;
                }
        }
    } else {
        float* Out = (float*)OutP;
#pragma unroll
        for (int n = 0; n < 4; ++n) {
            const int col = gc0 + n * 16 + fr;
            const float bb = bias[(size_t)e * NROWS + col];
#pragma unroll
            for (int m = 0; m < 8; ++m)
#pragma unroll
                for (int j = 0; j < 4; ++j) {
                    const int row = gr0 + m * 16 + fq * 4 + j;
                    Out[((size_t)e * MROWS + row) * NROWS + col] = acc[m][n][j] + bb;
                }
        }
    }
}

// ---------------------------------------------------------------------------
extern "C" void kernel_launch(void* const* d_in, const int* in_sizes, int n_in,
                              void* d_out, int out_size, void* d_ws, size_t ws_size,
                              hipStream_t stream)
{
    const float* x  = (const float*)d_in[0];
    const float* w1 = (const float*)d_in[1];
    const float* b1 = (const float*)d_in[2];
    const float* w2 = (const float*)d_in[3];
    const float* b2 = (const float*)d_in[4];
    float* out = (float*)d_out;

    (void)hipFuncSetAttribute(reinterpret_cast<const void*>(&gemm256_bk32<M_, true>),
                              hipFuncAttributeMaxDynamicSharedMemorySize, 65536);
    (void)hipFuncSetAttribute(reinterpret_cast<const void*>(&gemm256<H_, false>),
                              hipFuncAttributeMaxDynamicSharedMemorySize, 131072);

    const size_t xb_sz  = (size_t)E_ * C_ * M_ * sizeof(bf16);   //  32 MB
    const size_t w1b_sz = (size_t)E_ * H_ * M_ * sizeof(bf16);   // 256 MB
    const size_t w2t_sz = (size_t)E_ * O_ * H_ * sizeof(bf16);   // 256 MB
    const size_t y1_sz  = (size_t)E_ * C_ * H_ * sizeof(bf16);   // 128 MB

    if (ws_size >= xb_sz + w1b_sz + w2t_sz + y1_sz) {
        bf16* xb  = (bf16*)d_ws;
        bf16* w1b = (bf16*)((char*)d_ws + xb_sz);
        bf16* w2t = (bf16*)((char*)d_ws + xb_sz + w1b_sz);
        bf16* y1  = (bf16*)((char*)d_ws + xb_sz + w1b_sz + w2t_sz);

        cvt_f32_bf16<<<2048, 256, 0, stream>>>(x,  xb,  (size_t)E_ * C_ * M_);
        cvt_f32_bf16<<<2048, 256, 0, stream>>>(w1, w1b, (size_t)E_ * H_ * M_);
        transpose_w2<<<dim3(O_ / 64, H_ / 64, E_), 256, 0, stream>>>(w2, w2t, 0);

        // gemm1: BK=32, 64 KiB LDS, 2 blocks/CU; 1024 wgs = 2 rounds
        gemm256_bk32<M_, true><<<dim3(8 * 4 * (H_ / 256)), 512, 65536, stream>>>(
            xb, w1b, b1, y1, 4, H_ / 256);
        // gemm2: proven 8-phase BK=64; 256 wgs
        gemm256<H_, false><<<dim3(8 * 4 * (O_ / 256)), 512, 131072, stream>>>(
            y1, w2t, b2, out, 4, O_ / 256);
    } else {
        // per-expert fallback: ~84 MB of ws
        bf16* xb  = (bf16*)d_ws;
        bf16* w1b = (bf16*)((char*)d_ws + xb_sz / E_);
        bf16* w2t = (bf16*)((char*)d_ws + (xb_sz + w1b_sz) / E_);
        bf16* y1  = (bf16*)((char*)d_ws + (xb_sz + w1b_sz + w2t_sz) / E_);
        for (int e = 0; e < E_; ++e) {
            cvt_f32_bf16<<<512, 256, 0, stream>>>(x + (size_t)e * C_ * M_,  xb,  (size_t)C_ * M_);
            cvt_f32_bf16<<<2048, 256, 0, stream>>>(w1 + (size_t)e * H_ * M_, w1b, (size_t)H_ * M_);
            transpose_w2<<<dim3(O_ / 64, H_ / 64, 1), 256, 0, stream>>>(w2, w2t, e);
            gemm256_bk32<M_, true><<<dim3(4 * (H_ / 256)), 512, 65536, stream>>>(
                xb, w1b, b1 + (size_t)e * H_, y1, 4, H_ / 256);
            gemm256<H_, false><<<dim3(4 * (O_ / 256)), 512, 131072, stream>>>(
                y1, w2t, b2 + (size_t)e * O_, out + (size_t)e * C_ * O_, 4, O_ / 256);
        }
    }
}

// Round 8
// 908.103 us; speedup vs baseline: 2.8575x; 2.8575x over previous
//
#include <hip/hip_runtime.h>
#include <hip/hip_bf16.h>
#include <stddef.h>

// Problem constants
constexpr int E_ = 8;
constexpr int C_ = 1024;
constexpr int M_ = 2048;
constexpr int H_ = 8192;
constexpr int O_ = 2048;

typedef __bf16 bf16;
typedef __bf16 bf16x4 __attribute__((ext_vector_type(4)));
typedef __bf16 bf16x8 __attribute__((ext_vector_type(8)));
typedef float  f32x4  __attribute__((ext_vector_type(4)));

#define GLOAD16(src, dst)                                                        \
    __builtin_amdgcn_global_load_lds(                                            \
        (const __attribute__((address_space(1))) void*)(src),                    \
        (__attribute__((address_space(3))) void*)(dst), 16, 0, 0)

#define BARRIER()  __builtin_amdgcn_s_barrier()
#define LGKM0()    do { asm volatile("s_waitcnt lgkmcnt(0)" ::: "memory");       \
                        __builtin_amdgcn_sched_barrier(0); } while (0)
#define VMCNT(n)   asm volatile("s_waitcnt vmcnt(" #n ")" ::: "memory")

// ---------------------------------------------------------------------------
// fp32 -> bf16 convert (grid-stride, 64B-read/32B-write per lane per iter)
// ---------------------------------------------------------------------------
__global__ __launch_bounds__(256)
void cvt_f32_bf16(const float* __restrict__ in, bf16* __restrict__ out, size_t n)
{
    size_t i = ((size_t)blockIdx.x * blockDim.x + threadIdx.x) * 16;
    const size_t stride = (size_t)gridDim.x * blockDim.x * 16;
    for (; i < n; i += stride) {
        f32x4 v0 = *(const f32x4*)(in + i);
        f32x4 v1 = *(const f32x4*)(in + i + 4);
        f32x4 v2 = *(const f32x4*)(in + i + 8);
        f32x4 v3 = *(const f32x4*)(in + i + 12);
        bf16x8 o0, o1;
#pragma unroll
        for (int j = 0; j < 4; ++j) {
            o0[j] = (bf16)v0[j]; o0[j + 4] = (bf16)v1[j];
            o1[j] = (bf16)v2[j]; o1[j + 4] = (bf16)v3[j];
        }
        *(bf16x8*)(out + i)     = o0;
        *(bf16x8*)(out + i + 8) = o1;
    }
}

// ---------------------------------------------------------------------------
// Transpose+convert: W2 [E, H, O] fp32 -> W2t [gridDim.z, O, H] bf16
// ---------------------------------------------------------------------------
__global__ __launch_bounds__(256)
void transpose_w2(const float* __restrict__ W2, bf16* __restrict__ W2t, int e0)
{
    const int e  = e0 + blockIdx.z;
    const int oo = blockIdx.x;  // O/64
    const int ho = blockIdx.y;  // H/64
    const int tid = threadIdx.x;

    __shared__ bf16 t[64][72];  // 144B rows: 16B-aligned bf16x8 reads

    const float* src = W2 + (size_t)e * H_ * O_ + (size_t)(ho * 64) * O_ + oo * 64;
#pragma unroll
    for (int p = 0; p < 4; ++p) {
        const int h  = p * 16 + (tid >> 4);
        const int o4 = (tid & 15) * 4;
        f32x4 v = *(const f32x4*)(src + (size_t)h * O_ + o4);
#pragma unroll
        for (int q = 0; q < 4; ++q) t[o4 + q][h] = (bf16)v[q];
    }
    __syncthreads();

    bf16* dst = W2t + (size_t)blockIdx.z * O_ * H_ + (size_t)(oo * 64) * H_ + ho * 64;
#pragma unroll
    for (int p2 = 0; p2 < 2; ++p2) {
        const int o  = p2 * 32 + (tid >> 3);
        const int h8 = (tid & 7) * 8;
        bf16x8 v = *(const bf16x8*)(&t[o][h8]);
        *(bf16x8*)(dst + (size_t)o * H_ + h8) = v;
    }
}

// ---------------------------------------------------------------------------
// 256x256-tile 8-phase GEMM, BK=64, 128 KiB LDS, 8 waves (r3-proven).
// Used for gemm2 (K=8192).
// ---------------------------------------------------------------------------
template<int KDIM, bool RELU_BF16>
__global__ __launch_bounds__(512, 2)
void gemm256(const bf16* __restrict__ A, const bf16* __restrict__ B,
             const float* __restrict__ bias, void* __restrict__ OutP,
             int nBM, int nBN)
{
    extern __shared__ char smem[];                  // 131072 B
    constexpr int K2  = KDIM * 2;
    constexpr int NIT = KDIM / 128;

    const int tid  = threadIdx.x;
    const int lane = tid & 63;
    const int wid  = tid >> 6;
    const int wr = wid >> 2, wc = wid & 3;
    const int fr = lane & 15, fq = lane >> 4;

    const int nwg = gridDim.x;
    const int cpx = nwg >> 3;
    const int b0  = blockIdx.x;
    const int wg  = (b0 & 7) * cpx + (b0 >> 3);
    const int per_e = nBM * nBN;
    const int e  = wg / per_e;
    const int rr = wg - e * per_e;
    const int bn = rr / nBM;
    const int bm = rr - bn * nBM;
    const int MROWS = nBM * 256;
    const int NROWS = nBN * 256;

    const char* Apan = (const char*)(A + (size_t)e * MROWS * KDIM + (size_t)bm * 256 * KDIM);
    const char* Bpan = (const char*)(B + (size_t)e * NROWS * KDIM + (size_t)bn * 256 * KDIM);

    const int r0  = tid >> 3;
    const int wsw = ((tid & 7) << 4) ^ ((r0 & 7) << 4);

    auto stageA = [&](int gk, int comp) {
        char* lds = smem + (gk & 1) * 65536 + comp * 16384 + tid * 16;
        const char* src = Apan + (size_t)((comp << 7) + r0) * K2 + (size_t)gk * 128 + wsw;
        GLOAD16(src, lds);
        GLOAD16(src + (size_t)64 * K2, lds + 8192);
    };
    auto stageB = [&](int gk, int comp2) {
        char* lds = smem + (gk & 1) * 65536 + 32768 + comp2 * 16384 + tid * 16;
        const char* src = Bpan + (size_t)((comp2 << 7) + r0) * K2 + (size_t)gk * 128 + wsw;
        GLOAD16(src, lds);
        GLOAD16(src + (size_t)64 * K2, lds + 8192);
    };

    const int frq = fr & 7;
    const int cA0 = ((fq    ) ^ frq) << 4;
    const int cA1 = ((4 | fq) ^ frq) << 4;
    const int aoff = wr * 16384 + fr * 128;
    const int boff = 32768 + (wc >> 1) * 16384 + (wc & 1) * 8192 + fr * 128;

    bf16x8 av[4][2];
    bf16x8 bv[4][2];
    f32x4 acc[8][4];
#pragma unroll
    for (int m = 0; m < 8; ++m)
#pragma unroll
        for (int n = 0; n < 4; ++n) acc[m][n] = (f32x4){0.f, 0.f, 0.f, 0.f};

    auto loadA = [&](const char* base, int mh) {
#pragma unroll
        for (int mm = 0; mm < 4; ++mm) {
            const char* p = base + aoff + (mh * 4 + mm) * 2048;
            av[mm][0] = *(const bf16x8*)(p + cA0);
            av[mm][1] = *(const bf16x8*)(p + cA1);
        }
    };
    auto loadB = [&](const char* base, int nh) {
#pragma unroll
        for (int nn = 0; nn < 2; ++nn) {
            const char* p = base + boff + (nh * 2 + nn) * 2048;
            bv[nh * 2 + nn][0] = *(const bf16x8*)(p + cA0);
            bv[nh * 2 + nn][1] = *(const bf16x8*)(p + cA1);
        }
    };
    auto mmaq = [&](int mh, int nh) {
        __builtin_amdgcn_s_setprio(1);
#pragma unroll
        for (int mm = 0; mm < 4; ++mm)
#pragma unroll
            for (int nn = 0; nn < 2; ++nn) {
                const int m = mh * 4 + mm, n = nh * 2 + nn;
                acc[m][n] = __builtin_amdgcn_mfma_f32_16x16x32_bf16(av[mm][0], bv[n][0], acc[m][n], 0, 0, 0);
                acc[m][n] = __builtin_amdgcn_mfma_f32_16x16x32_bf16(av[mm][1], bv[n][1], acc[m][n], 0, 0, 0);
            }
        __builtin_amdgcn_s_setprio(0);
    };

    stageB(0, 0); stageB(0, 1); stageA(0, 0); stageA(0, 1);
    stageB(1, 0); stageB(1, 1);
    VMCNT(4);
    BARRIER();

    for (int t = 0; t < NIT; ++t) {
        const bool nl = (t + 1 < NIT);
        const char* d0b = smem;
        const char* d1b = smem + 65536;
        const int ga = 2 * t + 1;
        const int gb = 2 * t + 2;
        const int gc = 2 * t + 3;

        loadB(d0b, 0); loadA(d0b, 0);       // ph0
        stageA(ga, 0);
        BARRIER(); LGKM0();
        mmaq(0, 0);
        BARRIER();

        loadB(d0b, 1);                      // ph1
        stageA(ga, 1);
        BARRIER(); LGKM0();
        mmaq(0, 1);
        BARRIER();

        loadA(d0b, 1);                      // ph2
        if (nl) stageB(gb, 0);
        BARRIER(); LGKM0();
        mmaq(1, 1);
        BARRIER();

        if (nl) stageB(gb, 1);              // ph3
        BARRIER(); LGKM0();
        mmaq(1, 0);
        if (nl) { VMCNT(4); } else { VMCNT(0); }
        BARRIER();

        loadB(d1b, 0); loadA(d1b, 0);       // ph4
        if (nl) stageA(gb, 0);
        BARRIER(); LGKM0();
        mmaq(0, 0);
        BARRIER();

        loadB(d1b, 1);                      // ph5
        if (nl) stageA(gb, 1);
        BARRIER(); LGKM0();
        mmaq(0, 1);
        BARRIER();

        loadA(d1b, 1);                      // ph6
        if (nl) stageB(gc, 0);
        BARRIER(); LGKM0();
        mmaq(1, 1);
        BARRIER();

        if (nl) stageB(gc, 1);              // ph7
        BARRIER(); LGKM0();
        mmaq(1, 0);
        if (nl) {
            VMCNT(4);
            BARRIER();
        }
    }

    const int gr0 = bm * 256 + wr * 128;
    const int gc0 = bn * 256 + wc * 64;
    if constexpr (RELU_BF16) {
        bf16* Out = (bf16*)OutP;
#pragma unroll
        for (int n = 0; n < 4; ++n) {
            const int col = gc0 + n * 16 + fr;
            const float bb = bias[(size_t)e * NROWS + col];
#pragma unroll
            for (int m = 0; m < 8; ++m)
#pragma unroll
                for (int j = 0; j < 4; ++j) {
                    float v = acc[m][n][j] + bb;
                    v = v > 0.f ? v : 0.f;
                    const int row = gr0 + m * 16 + fq * 4 + j;
                    Out[((size_t)e * MROWS + row) * NROWS + col] = (bf16)v;
                }
        }
    } else {
        float* Out = (float*)OutP;
#pragma unroll
        for (int n = 0; n < 4; ++n) {
            const int col = gc0 + n * 16 + fr;
            const float bb = bias[(size_t)e * NROWS + col];
#pragma unroll
            for (int m = 0; m < 8; ++m)
#pragma unroll
                for (int j = 0; j < 4; ++j) {
                    const int row = gr0 + m * 16 + fq * 4 + j;
                    Out[((size_t)e * MROWS + row) * NROWS + col] = acc[m][n][j] + bb;
                }
        }
    }
}

// ---------------------------------------------------------------------------
// 16-WAVE variant of the same 256x256 BK=64 8-phase schedule (gemm1, K=2048).
// 1024 threads = 4M x 4N waves, wave tile 64x64: acc[4][4] (64 VGPR) +
// bv[4][2] (32) + av[2][2] reused (16) ~= 124 regs -> 4 waves/SIMD at
// 1 block/CU (vs 2 for the 8-wave kernel): doubles SIMD-level interleave to
// hide ds_read latency + barrier skew on the short-K GEMM. LDS layout,
// swizzle, stage stream, barrier/vmcnt discipline identical to gemm256;
// stage granularity: 1024 thr x 16B = one 16 KiB half-region per gload ->
// counted waits become VMCNT(2) (2 halves in flight behind the wait).
// ---------------------------------------------------------------------------
template<int KDIM, bool RELU_BF16>
__global__ __launch_bounds__(1024, 1)
void gemm256w16(const bf16* __restrict__ A, const bf16* __restrict__ B,
                const float* __restrict__ bias, void* __restrict__ OutP,
                int nBM, int nBN)
{
    extern __shared__ char smem[];                  // 131072 B
    constexpr int K2  = KDIM * 2;
    constexpr int NIT = KDIM / 128;

    const int tid  = threadIdx.x;
    const int lane = tid & 63;
    const int wid  = tid >> 6;                      // 0..15
    const int wr = wid >> 2, wc = wid & 3;          // 4M x 4N
    const int fr = lane & 15, fq = lane >> 4;

    const int nwg = gridDim.x;
    const int cpx = nwg >> 3;
    const int b0  = blockIdx.x;
    const int wg  = (b0 & 7) * cpx + (b0 >> 3);
    const int per_e = nBM * nBN;
    const int e  = wg / per_e;
    const int rr = wg - e * per_e;
    const int bn = rr / nBM;
    const int bm = rr - bn * nBM;      // bm fastest: B-panel sharers same XCD
    const int MROWS = nBM * 256;
    const int NROWS = nBN * 256;

    const char* Apan = (const char*)(A + (size_t)e * MROWS * KDIM + (size_t)bm * 256 * KDIM);
    const char* Bpan = (const char*)(B + (size_t)e * NROWS * KDIM + (size_t)bn * 256 * KDIM);

    // staging: 1024 thr x 16B = 16 KiB = one half-region per call
    const int r0  = tid >> 3;                       // 0..127
    const int wsw = ((tid & 7) << 4) ^ ((r0 & 7) << 4);

    auto stageA = [&](int gk, int comp) {
        char* lds = smem + (gk & 1) * 65536 + comp * 16384 + tid * 16;
        const char* src = Apan + (size_t)((comp << 7) + r0) * K2 + (size_t)gk * 128 + wsw;
        GLOAD16(src, lds);
    };
    auto stageB = [&](int gk, int comp2) {
        char* lds = smem + (gk & 1) * 65536 + 32768 + comp2 * 16384 + tid * 16;
        const char* src = Bpan + (size_t)((comp2 << 7) + r0) * K2 + (size_t)gk * 128 + wsw;
        GLOAD16(src, lds);
    };

    // fragment reads: rows 128B, chunk c = kk*4+fq swizzled by ^(fr&7)
    const int frq = fr & 7;
    const int cA0 = ((fq    ) ^ frq) << 4;
    const int cA1 = ((4 | fq) ^ frq) << 4;
    // wave wr covers M rows wr*64..+63: half = wr>>1, in-half base (wr&1)*64
    const int aoff = (wr >> 1) * 16384 + (wr & 1) * 8192 + fr * 128;
    const int boff = 32768 + (wc >> 1) * 16384 + (wc & 1) * 8192 + fr * 128;

    bf16x8 av[2][2];        // reused per m-half
    bf16x8 bv[4][2];        // all 4 n-frags live
    f32x4 acc[4][4];
#pragma unroll
    for (int m = 0; m < 4; ++m)
#pragma unroll
        for (int n = 0; n < 4; ++n) acc[m][n] = (f32x4){0.f, 0.f, 0.f, 0.f};

    auto loadA = [&](const char* base, int mh) {    // 2 m-frags x 2 kk = 4 reads
#pragma unroll
        for (int mm = 0; mm < 2; ++mm) {
            const char* p = base + aoff + (mh * 2 + mm) * 2048;
            av[mm][0] = *(const bf16x8*)(p + cA0);
            av[mm][1] = *(const bf16x8*)(p + cA1);
        }
    };
    auto loadB = [&](const char* base, int nh) {    // 2 n-frags x 2 kk = 4 reads
#pragma unroll
        for (int nn = 0; nn < 2; ++nn) {
            const char* p = base + boff + (nh * 2 + nn) * 2048;
            bv[nh * 2 + nn][0] = *(const bf16x8*)(p + cA0);
            bv[nh * 2 + nn][1] = *(const bf16x8*)(p + cA1);
        }
    };
    auto mmaq = [&](int mh, int nh) {               // 2m x 2n x 2kk = 8 MFMA
        __builtin_amdgcn_s_setprio(1);
#pragma unroll
        for (int mm = 0; mm < 2; ++mm)
#pragma unroll
            for (int nn = 0; nn < 2; ++nn) {
                const int m = mh * 2 + mm, n = nh * 2 + nn;
                acc[m][n] = __builtin_amdgcn_mfma_f32_16x16x32_bf16(av[mm][0], bv[n][0], acc[m][n], 0, 0, 0);
                acc[m][n] = __builtin_amdgcn_mfma_f32_16x16x32_bf16(av[mm][1], bv[n][1], acc[m][n], 0, 0, 0);
            }
        __builtin_amdgcn_s_setprio(0);
    };

    // prologue: 6 half-stages; retire tile 0 (4 oldest) -> VMCNT(2)
    stageB(0, 0); stageB(0, 1); stageA(0, 0); stageA(0, 1);
    stageB(1, 0); stageB(1, 1);
    VMCNT(2);
    BARRIER();

    for (int t = 0; t < NIT; ++t) {
        const bool nl = (t + 1 < NIT);
        const char* d0b = smem;
        const char* d1b = smem + 65536;
        const int ga = 2 * t + 1;
        const int gb = 2 * t + 2;
        const int gc = 2 * t + 3;

        loadB(d0b, 0); loadA(d0b, 0);       // ph0
        stageA(ga, 0);
        BARRIER(); LGKM0();
        mmaq(0, 0);
        BARRIER();

        loadB(d0b, 1);                      // ph1
        stageA(ga, 1);
        BARRIER(); LGKM0();
        mmaq(0, 1);
        BARRIER();

        loadA(d0b, 1);                      // ph2
        if (nl) stageB(gb, 0);
        BARRIER(); LGKM0();
        mmaq(1, 1);
        BARRIER();

        if (nl) stageB(gb, 1);              // ph3
        BARRIER(); LGKM0();
        mmaq(1, 0);
        if (nl) { VMCNT(2); } else { VMCNT(0); }   // ga's A resident
        BARRIER();

        loadB(d1b, 0); loadA(d1b, 0);       // ph4
        if (nl) stageA(gb, 0);
        BARRIER(); LGKM0();
        mmaq(0, 0);
        BARRIER();

        loadB(d1b, 1);                      // ph5
        if (nl) stageA(gb, 1);
        BARRIER(); LGKM0();
        mmaq(0, 1);
        BARRIER();

        loadA(d1b, 1);                      // ph6
        if (nl) stageB(gc, 0);
        BARRIER(); LGKM0();
        mmaq(1, 1);
        BARRIER();

        if (nl) stageB(gc, 1);              // ph7
        BARRIER(); LGKM0();
        mmaq(1, 0);
        if (nl) {
            VMCNT(2);                       // gb fully resident
            BARRIER();
        }
    }

    const int gr0 = bm * 256 + wr * 64;
    const int gc0 = bn * 256 + wc * 64;
    if constexpr (RELU_BF16) {
        bf16* Out = (bf16*)OutP;
#pragma unroll
        for (int n = 0; n < 4; ++n) {
            const int col = gc0 + n * 16 + fr;
            const float bb = bias[(size_t)e * NROWS + col];
#pragma unroll
            for (int m = 0; m < 4; ++m)
#pragma unroll
                for (int j = 0; j < 4; ++j) {
                    float v = acc[m][n][j] + bb;
                    v = v > 0.f ? v : 0.f;
                    const int row = gr0 + m * 16 + fq * 4 + j;
                    Out[((size_t)e * MROWS + row) * NROWS + col] = (bf16)v;
                }
        }
    } else {
        float* Out = (float*)OutP;
#pragma unroll
        for (int n = 0; n < 4; ++n) {
            const int col = gc0 + n * 16 + fr;
            const float bb = bias[(size_t)e * NROWS + col];
#pragma unroll
            for (int m = 0; m < 4; ++m)
#pragma unroll
                for (int j = 0; j < 4; ++j) {
                    const int row = gr0 + m * 16 + fq * 4 + j;
                    Out[((size_t)e * MROWS + row) * NROWS + col] = acc[m][n][j] + bb;
                }
        }
    }
}

// ---------------------------------------------------------------------------
extern "C" void kernel_launch(void* const* d_in, const int* in_sizes, int n_in,
                              void* d_out, int out_size, void* d_ws, size_t ws_size,
                              hipStream_t stream)
{
    const float* x  = (const float*)d_in[0];
    const float* w1 = (const float*)d_in[1];
    const float* b1 = (const float*)d_in[2];
    const float* w2 = (const float*)d_in[3];
    const float* b2 = (const float*)d_in[4];
    float* out = (float*)d_out;

    (void)hipFuncSetAttribute(reinterpret_cast<const void*>(&gemm256w16<M_, true>),
                              hipFuncAttributeMaxDynamicSharedMemorySize, 131072);
    (void)hipFuncSetAttribute(reinterpret_cast<const void*>(&gemm256<H_, false>),
                              hipFuncAttributeMaxDynamicSharedMemorySize, 131072);

    const size_t xb_sz  = (size_t)E_ * C_ * M_ * sizeof(bf16);   //  32 MB
    const size_t w1b_sz = (size_t)E_ * H_ * M_ * sizeof(bf16);   // 256 MB
    const size_t w2t_sz = (size_t)E_ * O_ * H_ * sizeof(bf16);   // 256 MB
    const size_t y1_sz  = (size_t)E_ * C_ * H_ * sizeof(bf16);   // 128 MB

    if (ws_size >= xb_sz + w1b_sz + w2t_sz + y1_sz) {
        bf16* xb  = (bf16*)d_ws;
        bf16* w1b = (bf16*)((char*)d_ws + xb_sz);
        bf16* w2t = (bf16*)((char*)d_ws + xb_sz + w1b_sz);
        bf16* y1  = (bf16*)((char*)d_ws + xb_sz + w1b_sz + w2t_sz);

        cvt_f32_bf16<<<2048, 256, 0, stream>>>(x,  xb,  (size_t)E_ * C_ * M_);
        cvt_f32_bf16<<<2048, 256, 0, stream>>>(w1, w1b, (size_t)E_ * H_ * M_);
        transpose_w2<<<dim3(O_ / 64, H_ / 64, E_), 256, 0, stream>>>(w2, w2t, 0);

        // gemm1: 16-wave variant, 1024 wgs
        gemm256w16<M_, true><<<dim3(8 * 4 * (H_ / 256)), 1024, 131072, stream>>>(
            xb, w1b, b1, y1, 4, H_ / 256);
        // gemm2: proven 8-wave 8-phase, 256 wgs
        gemm256<H_, false><<<dim3(8 * 4 * (O_ / 256)), 512, 131072, stream>>>(
            y1, w2t, b2, out, 4, O_ / 256);
    } else {
        // per-expert fallback: ~84 MB of ws
        bf16* xb  = (bf16*)d_ws;
        bf16* w1b = (bf16*)((char*)d_ws + xb_sz / E_);
        bf16* w2t = (bf16*)((char*)d_ws + (xb_sz + w1b_sz) / E_);
        bf16* y1  = (bf16*)((char*)d_ws + (xb_sz + w1b_sz + w2t_sz) / E_);
        for (int e = 0; e < E_; ++e) {
            cvt_f32_bf16<<<512, 256, 0, stream>>>(x + (size_t)e * C_ * M_,  xb,  (size_t)C_ * M_);
            cvt_f32_bf16<<<2048, 256, 0, stream>>>(w1 + (size_t)e * H_ * M_, w1b, (size_t)H_ * M_);
            transpose_w2<<<dim3(O_ / 64, H_ / 64, 1), 256, 0, stream>>>(w2, w2t, e);
            gemm256w16<M_, true><<<dim3(4 * (H_ / 256)), 1024, 131072, stream>>>(
                xb, w1b, b1 + (size_t)e * H_, y1, 4, H_ / 256);
            gemm256<H_, false><<<dim3(4 * (O_ / 256)), 512, 131072, stream>>>(
                y1, w2t, b2 + (size_t)e * O_, out + (size_t)e * C_ * O_, 4, O_ / 256);
        }
    }
}